// Round 10
// baseline (89.091 us; speedup 1.0000x reference)
//
#include <hip/hip_runtime.h>
#include <hip/hip_bf16.h>
#include <math.h>

#define C_DIM 128
#define B_DIM 4
#define N_DIM 8192
#define M_DIM 2048
#define NT_KV 32   // M_DIM / 64 (64-m tiles, proj-side granularity)

typedef unsigned short u16;
typedef unsigned int u32;
typedef short bf16x8 __attribute__((ext_vector_type(8)));
typedef float f32x4 __attribute__((ext_vector_type(4)));
typedef float f32x16 __attribute__((ext_vector_type(16)));
typedef u32 u32x4 __attribute__((ext_vector_type(4)));

__device__ inline u16 f2bf(float f) {
  u32 u = __builtin_bit_cast(u32, f);
  u += 0x7fffu + ((u >> 16) & 1u);  // RNE, finite inputs
  return (u16)(u >> 16);
}
__device__ inline u32 cvtpk_bf16(float lo, float hi) {
  u32 r;
  asm("v_cvt_pk_bf16_f32 %0, %1, %2" : "=v"(r) : "v"(lo), "v"(hi));
  return r;
}

// ---------------- Projections: Y = W @ X_b, MFMA 16x16x32 ----------------
// MODE 0: Qt bf16 [b][x][o]; MODE 2: K frag-major; MODE 3: V frag-major.
template <int MODE>
__device__ inline void proj_pass(const float* __restrict__ W, float wscale,
                                 const u16* __restrict__ xt_s,
                                 u16* __restrict__ outh,
                                 int b, int X, int x0, int t) {
  const int l = t & 63, w = t >> 6, lr = l & 15, lh = (l >> 4) & 3;
  bf16x8 wf[2][4];
  #pragma unroll
  for (int ot = 0; ot < 2; ++ot)
    #pragma unroll
    for (int kc = 0; kc < 4; ++kc) {
      const float* wp = &W[(size_t)(w * 32 + ot * 16 + lr) * 128 + kc * 32 + lh * 8];
      float4 a0 = *(const float4*)wp;
      float4 a1 = *(const float4*)(wp + 4);
      bf16x8 f;
      f[0] = (short)f2bf(a0.x * wscale); f[1] = (short)f2bf(a0.y * wscale);
      f[2] = (short)f2bf(a0.z * wscale); f[3] = (short)f2bf(a0.w * wscale);
      f[4] = (short)f2bf(a1.x * wscale); f[5] = (short)f2bf(a1.y * wscale);
      f[6] = (short)f2bf(a1.z * wscale); f[7] = (short)f2bf(a1.w * wscale);
      wf[ot][kc] = f;
    }
  f32x4 acc[2][4];
  #pragma unroll
  for (int ot = 0; ot < 2; ++ot)
    #pragma unroll
    for (int xt = 0; xt < 4; ++xt) acc[ot][xt] = 0.f;

  #pragma unroll
  for (int xt = 0; xt < 4; ++xt) {
    int xx = xt * 16 + lr;
    #pragma unroll
    for (int kc = 0; kc < 4; ++kc) {
      bf16x8 bf = *(const bf16x8*)&xt_s[xx * 128 + ((kc * 32 + lh * 8) ^ ((xx & 15) << 3))];
      #pragma unroll
      for (int ot = 0; ot < 2; ++ot)
        acc[ot][xt] = __builtin_amdgcn_mfma_f32_16x16x32_bf16(wf[ot][kc], bf, acc[ot][xt], 0, 0, 0);
    }
  }
  #pragma unroll
  for (int ot = 0; ot < 2; ++ot) {
    int o0 = w * 32 + ot * 16 + lh * 4;
    #pragma unroll
    for (int xt = 0; xt < 4; ++xt) {
      int xg = x0 + xt * 16 + lr;
      if constexpr (MODE == 0) {
        u16 h[4];
        #pragma unroll
        for (int r = 0; r < 4; ++r) h[r] = f2bf(acc[ot][xt][r]);
        *(uint2*)&outh[((size_t)b * X + xg) * 128 + o0] = *(uint2*)h;
      } else if constexpr (MODE == 2) {
        int tt = xg >> 6, mt = (xg >> 5) & 1, ms = xg & 31;
        int kcK = o0 >> 4, lh1p = (o0 >> 3) & 1, e0 = o0 & 7;
        u16 h[4];
        #pragma unroll
        for (int r = 0; r < 4; ++r) h[r] = f2bf(acc[ot][xt][r]);
        size_t off = ((((size_t)(b * NT_KV + tt) * 2 + mt) * 8 + kcK) * 64 + (ms | (lh1p << 5))) * 8 + e0;
        *(uint2*)&outh[off] = *(uint2*)h;
      } else {
        int tt = xg >> 6, sv = (xg >> 4) & 3, lh1m = (xg >> 3) & 1, e = xg & 7;
        int ctv = o0 >> 5;
        #pragma unroll
        for (int r = 0; r < 4; ++r) {
          int cs = (o0 + r) & 31;
          size_t off = ((((size_t)(b * NT_KV + tt) * 4 + ctv) * 4 + sv) * 64 + (cs | (lh1m << 5))) * 8 + e;
          outh[off] = f2bf(acc[ot][xt][r]);
        }
      }
    }
  }
}

template <int MODE_A, int MODE_B>
__global__ __launch_bounds__(256, 2) void proj_kernel(
    const float* __restrict__ in, const float* __restrict__ WA, const float* __restrict__ WB,
    u16* __restrict__ hA, u16* __restrict__ hB, int X, float wscaleA) {
  __shared__ u16 xt_s[64 * 128];
  const int b = blockIdx.y, x0 = blockIdx.x * 64, t = threadIdx.x;
  #pragma unroll
  for (int pp = 0; pp < 8; ++pp) {
    int c = pp * 16 + (t >> 4);
    int x4 = (t & 15) * 4;
    float4 v = *(const float4*)&in[((size_t)b * 128 + c) * X + x0 + x4];
    xt_s[(x4 + 0) * 128 + (c ^ (((x4 + 0) & 15) << 3))] = f2bf(v.x);
    xt_s[(x4 + 1) * 128 + (c ^ (((x4 + 1) & 15) << 3))] = f2bf(v.y);
    xt_s[(x4 + 2) * 128 + (c ^ (((x4 + 2) & 15) << 3))] = f2bf(v.z);
    xt_s[(x4 + 3) * 128 + (c ^ (((x4 + 3) & 15) << 3))] = f2bf(v.w);
  }
  __syncthreads();
  proj_pass<MODE_A>(WA, wscaleA, xt_s, hA, b, X, x0, t);
  if constexpr (MODE_B >= 0)
    proj_pass<MODE_B>(WB, 1.0f, xt_s, hB, b, X, x0, t);
}

// ---------------- Flash attention, 32x32x16, swapped QK^T ----------------
// 256 blocks x 1024 thr (16 waves, 4/SIMD forced via launch_bounds).
// Block = 128 q; wave w: q-slot w&3, m-quarter h=w>>2 of each 128-m tile.
// 16 iters of 128-m tiles (K+V staged contiguously, dbuf 128 KB).
// Non-deferred PV (V ds_read in PV phase; TLP hides the chain at 4/SIMD).
// No-max softmax; 4-way additive merge in 3 LDS rounds; fused skip epilogue.
__device__ inline void stage_kv(const u16* __restrict__ gK, const u16* __restrict__ gV,
                                u16* lK, u16* lV, int tile, int t) {
  const u16* ks = gK + (size_t)tile * 16384;
  const u16* vs = gV + (size_t)tile * 16384;
  #pragma unroll
  for (int i = 0; i < 2; ++i) {
    int ch = t + i * 1024;
    __builtin_amdgcn_global_load_lds((const __attribute__((address_space(1))) void*)(ks + ch * 8),
                                     (__attribute__((address_space(3))) void*)(lK + ch * 8), 16, 0, 0);
    __builtin_amdgcn_global_load_lds((const __attribute__((address_space(1))) void*)(vs + ch * 8),
                                     (__attribute__((address_space(3))) void*)(lV + ch * 8), 16, 0, 0);
  }
}

__global__ __launch_bounds__(1024, 4) void attn_kernel(
    const u16* __restrict__ Qt, const u16* __restrict__ Kt2,
    const u16* __restrict__ Vp, const float* __restrict__ up,
    const float* __restrict__ wskip, float* __restrict__ out) {
  __shared__ union {
    u16 kv[2][2][16384];   // [dbuf][K/V] 128-m tiles = 128 KB
    float od[8][4096];     // merge dump regions (16 KB each)
  } lds;
  __shared__ float lb1[8][64];
  __shared__ float lb2[4][64];

  const int bid = blockIdx.x;
  const int xcd = bid & 7, b = xcd & 3, slot = bid >> 3;  // batch pinned per XCD pair
  const int n0 = ((xcd >> 2) * 32 + slot) * 128;
  const int t = threadIdx.x, w = t >> 6, l = t & 63, lh1 = l >> 5;
  const int h = w >> 2;          // m-quarter within each 128-m tile
  const int nq = n0 + (w & 3) * 32 + (l & 31);

  // Q fragments (B[k=c][j=q]): q = l&31, c = kc*16 + lh1*8 + e
  bf16x8 qf[8];
  #pragma unroll
  for (int kc = 0; kc < 8; ++kc)
    qf[kc] = *(const bf16x8*)&Qt[((size_t)b * N_DIM + nq) * 128 + kc * 16 + lh1 * 8];

  const u16* gK = Kt2 + (size_t)b * 262144;
  const u16* gV = Vp + (size_t)b * 262144;

  f32x16 acco[4];
  #pragma unroll
  for (int ct = 0; ct < 4; ++ct) acco[ct] = 0.f;
  float lrun = 0.f;

  stage_kv(gK, gV, lds.kv[0][0], lds.kv[0][1], 0, t);
  __syncthreads();

  for (int i = 0; i < 16; ++i) {
    const int cur = i & 1;
    if (i + 1 < 16)
      stage_kv(gK, gV, lds.kv[cur ^ 1][0], lds.kv[cur ^ 1][1], i + 1, t);
    const u16* kl = lds.kv[cur][0];
    const u16* vl = lds.kv[cur][1];

    // --- QK(i): this wave's 32-m quarter (8 MFMAs) ---
    f32x16 sacc = 0.f;
    __builtin_amdgcn_s_setprio(1);
    #pragma unroll
    for (int kc = 0; kc < 8; ++kc) {
      bf16x8 kf = *(const bf16x8*)&kl[((h * 8 + kc) * 64 + l) * 8];
      sacc = __builtin_amdgcn_mfma_f32_32x32x16_bf16(kf, qf[kc], sacc, 0, 0, 0);
    }
    __builtin_amdgcn_s_setprio(0);

    // --- softmax(i), no max: P = exp2(S); pairwise tree-sum ---
    #pragma unroll
    for (int r = 0; r < 16; ++r) sacc[r] = exp2f(sacc[r]);
    {
      float a0 = (sacc[0] + sacc[1]) + (sacc[2] + sacc[3]);
      float a1 = (sacc[4] + sacc[5]) + (sacc[6] + sacc[7]);
      float a2 = (sacc[8] + sacc[9]) + (sacc[10] + sacc[11]);
      float a3 = (sacc[12] + sacc[13]) + (sacc[14] + sacc[15]);
      lrun += (a0 + a1) + (a2 + a3);
    }
    // --- pack + permlane32_swap exchange -> PV B-fragments ---
    u32 gp[4][2];
    #pragma unroll
    for (int j = 0; j < 4; ++j) {
      gp[j][0] = cvtpk_bf16(sacc[j * 4 + 0], sacc[j * 4 + 1]);
      gp[j][1] = cvtpk_bf16(sacc[j * 4 + 2], sacc[j * 4 + 3]);
    }
    bf16x8 pf[2];
    #pragma unroll
    for (int u = 0; u < 2; ++u) {
      u32 a0 = gp[2 * u][0], a1 = gp[2 * u][1];
      u32 b0 = gp[2 * u + 1][0], b1 = gp[2 * u + 1][1];
      asm("v_permlane32_swap_b32 %0, %1" : "+v"(a0), "+v"(b0));
      asm("v_permlane32_swap_b32 %0, %1" : "+v"(a1), "+v"(b1));
      u32x4 fv; fv.x = a0; fv.y = a1; fv.z = b0; fv.w = b1;
      pf[u] = __builtin_bit_cast(bf16x8, fv);
    }

    // --- PV(i): V frags from LDS (this quarter), 8 MFMAs ---
    const u16* vq = vl + (size_t)(h >> 1) * 8192;
    __builtin_amdgcn_s_setprio(1);
    #pragma unroll
    for (int u = 0; u < 2; ++u)
      #pragma unroll
      for (int ct = 0; ct < 4; ++ct) {
        bf16x8 vf = *(const bf16x8*)&vq[((ct * 4 + (h & 1) * 2 + u) * 64 + l) * 8];
        acco[ct] = __builtin_amdgcn_mfma_f32_32x32x16_bf16(vf, pf[u], acco[ct], 0, 0, 0);
      }
    __builtin_amdgcn_s_setprio(0);
    __syncthreads();   // drains stage(i+1) + protects dbuf swap
  }

  float lt = lrun + __shfl_xor(lrun, 32, 64);

  // --- 4-way additive merge, 3 LDS rounds (od aliases retired kv) ---
  if (w >= 8) {
    float* dst = lds.od[w - 8];
    #pragma unroll
    for (int ct = 0; ct < 4; ++ct)
      #pragma unroll
      for (int r = 0; r < 16; ++r) dst[(ct * 16 + r) * 64 + l] = acco[ct][r];
    lb1[w - 8][l] = lt;
  }
  __syncthreads();
  if (w < 8) {
    const float* src = lds.od[w];
    #pragma unroll
    for (int ct = 0; ct < 4; ++ct)
      #pragma unroll
      for (int r = 0; r < 16; ++r) acco[ct][r] += src[(ct * 16 + r) * 64 + l];
    lt += lb1[w][l];
  }
  __syncthreads();
  if (w >= 4 && w < 8) {
    float* dst = lds.od[w - 4];
    #pragma unroll
    for (int ct = 0; ct < 4; ++ct)
      #pragma unroll
      for (int r = 0; r < 16; ++r) dst[(ct * 16 + r) * 64 + l] = acco[ct][r];
    lb2[w - 4][l] = lt;
  }
  __syncthreads();
  if (w < 4) {
    const float* src = lds.od[w];
    #pragma unroll
    for (int ct = 0; ct < 4; ++ct)
      #pragma unroll
      for (int r = 0; r < 16; ++r) acco[ct][r] += src[(ct * 16 + r) * 64 + l];
    lt += lb2[w][l];

    // --- normalize, then fuse skip = wskip @ up via MFMA into acco ---
    float inv = 1.0f / lt;
    #pragma unroll
    for (int ct = 0; ct < 4; ++ct)
      #pragma unroll
      for (int r = 0; r < 16; ++r) acco[ct][r] *= inv;

    const float* upb = up + (size_t)b * 128 * N_DIM;
    #pragma unroll
    for (int kc = 0; kc < 8; ++kc) {
      float uv[8];
      #pragma unroll
      for (int e = 0; e < 8; ++e)
        uv[e] = upb[(size_t)(kc * 16 + lh1 * 8 + e) * N_DIM + nq];
      u32x4 ufv;
      ufv.x = cvtpk_bf16(uv[0], uv[1]);
      ufv.y = cvtpk_bf16(uv[2], uv[3]);
      ufv.z = cvtpk_bf16(uv[4], uv[5]);
      ufv.w = cvtpk_bf16(uv[6], uv[7]);
      bf16x8 upf = __builtin_bit_cast(bf16x8, ufv);
      #pragma unroll
      for (int ct = 0; ct < 4; ++ct) {
        const float* wp = &wskip[(size_t)(ct * 32 + (l & 31)) * 128 + kc * 16 + lh1 * 8];
        float4 w0 = *(const float4*)wp;
        float4 w1 = *(const float4*)(wp + 4);
        u32x4 wfv;
        wfv.x = cvtpk_bf16(w0.x, w0.y);
        wfv.y = cvtpk_bf16(w0.z, w0.w);
        wfv.z = cvtpk_bf16(w1.x, w1.y);
        wfv.w = cvtpk_bf16(w1.z, w1.w);
        bf16x8 wsf = __builtin_bit_cast(bf16x8, wfv);
        acco[ct] = __builtin_amdgcn_mfma_f32_32x32x16_bf16(wsf, upf, acco[ct], 0, 0, 0);
      }
    }

    // --- store (single write; d_out never read) ---
    #pragma unroll
    for (int ct = 0; ct < 4; ++ct)
      #pragma unroll
      for (int r = 0; r < 16; ++r) {
        int c = ct * 32 + (r & 3) + 8 * (r >> 2) + 4 * lh1;
        out[((size_t)b * 128 + c) * N_DIM + nq] = acco[ct][r];
      }
  }
}

extern "C" void kernel_launch(void* const* d_in, const int* in_sizes, int n_in,
                              void* d_out, int out_size, void* d_ws, size_t ws_size,
                              hipStream_t stream) {
  const float* up    = (const float*)d_in[0];
  const float* down  = (const float*)d_in[1];
  const float* wq    = (const float*)d_in[2];
  const float* wk    = (const float*)d_in[3];
  const float* wv    = (const float*)d_in[4];
  const float* wskip = (const float*)d_in[5];
  float* out = (float*)d_out;

  u16* Qt  = (u16*)d_ws;                                   // 8 MB  [b][n][c]
  u16* Kt2 = Qt + (size_t)B_DIM * N_DIM * C_DIM;           // 2 MB  frag-major
  u16* Vp  = Kt2 + (size_t)B_DIM * M_DIM * C_DIM;          // 2 MB  frag-major

  const float qscale = (float)(1.4426950408889634 / sqrt(128.0));  // log2e/sqrt(C)

  hipLaunchKernelGGL((proj_kernel<0, -1>), dim3(N_DIM / 64, B_DIM), dim3(256), 0, stream,
                     up, wq, nullptr, Qt, nullptr, N_DIM, qscale);
  hipLaunchKernelGGL((proj_kernel<2, 3>), dim3(M_DIM / 64, B_DIM), dim3(256), 0, stream,
                     down, wk, wv, Kt2, Vp, M_DIM, 1.0f);
  hipLaunchKernelGGL((attn_kernel), dim3(256), dim3(1024), 0, stream,
                     Qt, Kt2, Vp, up, wskip, out);
}

// Round 11
// 78.191 us; speedup vs baseline: 1.1394x; 1.1394x over previous
//
#include <hip/hip_runtime.h>
#include <hip/hip_bf16.h>
#include <math.h>

#define C_DIM 128
#define B_DIM 4
#define N_DIM 8192
#define M_DIM 2048
#define NT_KV 32   // M_DIM / 64 (64-m tiles)

typedef unsigned short u16;
typedef unsigned int u32;
typedef short bf16x8 __attribute__((ext_vector_type(8)));
typedef float f32x4 __attribute__((ext_vector_type(4)));
typedef float f32x16 __attribute__((ext_vector_type(16)));
typedef u32 u32x4 __attribute__((ext_vector_type(4)));

__device__ inline u16 f2bf(float f) {
  u32 u = __builtin_bit_cast(u32, f);
  u += 0x7fffu + ((u >> 16) & 1u);  // RNE, finite inputs
  return (u16)(u >> 16);
}
__device__ inline u32 cvtpk_bf16(float lo, float hi) {
  u32 r;
  asm("v_cvt_pk_bf16_f32 %0, %1, %2" : "=v"(r) : "v"(lo), "v"(hi));
  return r;
}

// ---------------- Projections: Y = W @ X_b, MFMA 16x16x32 ----------------
// MODE 0: Qt bf16 [b][x][o]; MODE 2: K frag-major; MODE 3: V frag-major.
template <int MODE>
__device__ inline void proj_pass(const float* __restrict__ W, float wscale,
                                 const u16* __restrict__ xt_s,
                                 u16* __restrict__ outh,
                                 int b, int X, int x0, int t) {
  const int l = t & 63, w = t >> 6, lr = l & 15, lh = (l >> 4) & 3;
  bf16x8 wf[2][4];
  #pragma unroll
  for (int ot = 0; ot < 2; ++ot)
    #pragma unroll
    for (int kc = 0; kc < 4; ++kc) {
      const float* wp = &W[(size_t)(w * 32 + ot * 16 + lr) * 128 + kc * 32 + lh * 8];
      float4 a0 = *(const float4*)wp;
      float4 a1 = *(const float4*)(wp + 4);
      bf16x8 f;
      f[0] = (short)f2bf(a0.x * wscale); f[1] = (short)f2bf(a0.y * wscale);
      f[2] = (short)f2bf(a0.z * wscale); f[3] = (short)f2bf(a0.w * wscale);
      f[4] = (short)f2bf(a1.x * wscale); f[5] = (short)f2bf(a1.y * wscale);
      f[6] = (short)f2bf(a1.z * wscale); f[7] = (short)f2bf(a1.w * wscale);
      wf[ot][kc] = f;
    }
  f32x4 acc[2][4];
  #pragma unroll
  for (int ot = 0; ot < 2; ++ot)
    #pragma unroll
    for (int xt = 0; xt < 4; ++xt) acc[ot][xt] = 0.f;

  #pragma unroll
  for (int xt = 0; xt < 4; ++xt) {
    int xx = xt * 16 + lr;
    #pragma unroll
    for (int kc = 0; kc < 4; ++kc) {
      bf16x8 bf = *(const bf16x8*)&xt_s[xx * 128 + ((kc * 32 + lh * 8) ^ ((xx & 15) << 3))];
      #pragma unroll
      for (int ot = 0; ot < 2; ++ot)
        acc[ot][xt] = __builtin_amdgcn_mfma_f32_16x16x32_bf16(wf[ot][kc], bf, acc[ot][xt], 0, 0, 0);
    }
  }
  #pragma unroll
  for (int ot = 0; ot < 2; ++ot) {
    int o0 = w * 32 + ot * 16 + lh * 4;
    #pragma unroll
    for (int xt = 0; xt < 4; ++xt) {
      int xg = x0 + xt * 16 + lr;
      if constexpr (MODE == 0) {
        u16 h[4];
        #pragma unroll
        for (int r = 0; r < 4; ++r) h[r] = f2bf(acc[ot][xt][r]);
        *(uint2*)&outh[((size_t)b * X + xg) * 128 + o0] = *(uint2*)h;
      } else if constexpr (MODE == 2) {
        int tt = xg >> 6, mt = (xg >> 5) & 1, ms = xg & 31;
        int kcK = o0 >> 4, lh1p = (o0 >> 3) & 1, e0 = o0 & 7;
        u16 h[4];
        #pragma unroll
        for (int r = 0; r < 4; ++r) h[r] = f2bf(acc[ot][xt][r]);
        size_t off = ((((size_t)(b * NT_KV + tt) * 2 + mt) * 8 + kcK) * 64 + (ms | (lh1p << 5))) * 8 + e0;
        *(uint2*)&outh[off] = *(uint2*)h;
      } else {
        int tt = xg >> 6, sv = (xg >> 4) & 3, lh1m = (xg >> 3) & 1, e = xg & 7;
        int ctv = o0 >> 5;
        #pragma unroll
        for (int r = 0; r < 4; ++r) {
          int cs = (o0 + r) & 31;
          size_t off = ((((size_t)(b * NT_KV + tt) * 4 + ctv) * 4 + sv) * 64 + (cs | (lh1m << 5))) * 8 + e;
          outh[off] = f2bf(acc[ot][xt][r]);
        }
      }
    }
  }
}

template <int MODE_A, int MODE_B>
__global__ __launch_bounds__(256, 2) void proj_kernel(
    const float* __restrict__ in, const float* __restrict__ WA, const float* __restrict__ WB,
    u16* __restrict__ hA, u16* __restrict__ hB, int X, float wscaleA) {
  __shared__ u16 xt_s[64 * 128];
  const int b = blockIdx.y, x0 = blockIdx.x * 64, t = threadIdx.x;
  #pragma unroll
  for (int pp = 0; pp < 8; ++pp) {
    int c = pp * 16 + (t >> 4);
    int x4 = (t & 15) * 4;
    float4 v = *(const float4*)&in[((size_t)b * 128 + c) * X + x0 + x4];
    xt_s[(x4 + 0) * 128 + (c ^ (((x4 + 0) & 15) << 3))] = f2bf(v.x);
    xt_s[(x4 + 1) * 128 + (c ^ (((x4 + 1) & 15) << 3))] = f2bf(v.y);
    xt_s[(x4 + 2) * 128 + (c ^ (((x4 + 2) & 15) << 3))] = f2bf(v.z);
    xt_s[(x4 + 3) * 128 + (c ^ (((x4 + 3) & 15) << 3))] = f2bf(v.w);
  }
  __syncthreads();
  proj_pass<MODE_A>(WA, wscaleA, xt_s, hA, b, X, x0, t);
  if constexpr (MODE_B >= 0)
    proj_pass<MODE_B>(WB, 1.0f, xt_s, hB, b, X, x0, t);
}

// ---------------- Flash attention, 32x32x16, swapped QK^T ----------------
// 512 blocks x 256 thr (4 waves). Block = 64 q; wave w: q-slot w&1,
// m-half h=w>>1. 64 KB dbuf -> 2 INDEPENDENT blocks/CU (separate barrier
// domains; block A computes through block B's barrier drain). Inner loop
// identical to R9: deferred register-PV overlapping QK, no-max softmax,
// permlane32_swap P-exchange, 2-way additive LDS merge, fused skip.
__device__ inline void stage_kv(const u16* __restrict__ gK, const u16* __restrict__ gV,
                                u16* lK, u16* lV, int tile, int t) {
  const u16* ks = gK + (size_t)tile * 8192;
  const u16* vs = gV + (size_t)tile * 8192;
  #pragma unroll
  for (int i = 0; i < 4; ++i) {
    int ch = t + i * 256;
    __builtin_amdgcn_global_load_lds((const __attribute__((address_space(1))) void*)(ks + ch * 8),
                                     (__attribute__((address_space(3))) void*)(lK + ch * 8), 16, 0, 0);
    __builtin_amdgcn_global_load_lds((const __attribute__((address_space(1))) void*)(vs + ch * 8),
                                     (__attribute__((address_space(3))) void*)(lV + ch * 8), 16, 0, 0);
  }
}

__global__ __launch_bounds__(256, 2) void attn_kernel(
    const u16* __restrict__ Qt, const u16* __restrict__ Kt2,
    const u16* __restrict__ Vp, const float* __restrict__ up,
    const float* __restrict__ wskip, float* __restrict__ out) {
  __shared__ union {
    u16 kv[2][2][8192];   // [dbuf][K/V] = 64 KB
    float od[2][4096];    // merge: waves 2,3 dump unnormalized O (32 KB)
  } lds;
  __shared__ float lb[2][64];

  const int bid = blockIdx.x;
  const int xcd = bid & 7, b = xcd & 3, slot = bid >> 3;  // batch pinned per XCD pair
  const int n0 = ((xcd >> 2) * 64 + slot) * 64;
  const int t = threadIdx.x, w = t >> 6, l = t & 63, lh1 = l >> 5;
  const int h = w >> 1;          // m-half (mt)
  const int nq = n0 + (w & 1) * 32 + (l & 31);

  // Q fragments (B[k=c][j=q]): q = l&31, c = kc*16 + lh1*8 + e
  bf16x8 qf[8];
  #pragma unroll
  for (int kc = 0; kc < 8; ++kc)
    qf[kc] = *(const bf16x8*)&Qt[((size_t)b * N_DIM + nq) * 128 + kc * 16 + lh1 * 8];

  const u16* gK = Kt2 + (size_t)b * 262144;
  const u16* gV = Vp + (size_t)b * 262144;

  f32x16 acco[4];
  #pragma unroll
  for (int ct = 0; ct < 4; ++ct) acco[ct] = 0.f;
  float lrun = 0.f;

  // Deferred-PV state (zero-init so PV(-1) adds 0).
  bf16x8 pf[2];
  bf16x8 vreg[8];
  #pragma unroll
  for (int u = 0; u < 2; ++u) pf[u] = (bf16x8)0;
  #pragma unroll
  for (int x = 0; x < 8; ++x) vreg[x] = (bf16x8)0;

  stage_kv(gK, gV, lds.kv[0][0], lds.kv[0][1], 0, t);
  __syncthreads();

  #pragma unroll 2
  for (int i = 0; i < NT_KV; ++i) {
    const int cur = i & 1;
    if (i + 1 < NT_KV)
      stage_kv(gK, gV, lds.kv[cur ^ 1][0], lds.kv[cur ^ 1][1], i + 1, t);
    const u16* kl = lds.kv[cur][0];
    const u16* vl = lds.kv[cur][1];

    // --- QK(i): this wave's m-half only (8 MFMAs, one sacc chain) ---
    f32x16 sacc = 0.f;
    __builtin_amdgcn_s_setprio(1);
    #pragma unroll
    for (int kc = 0; kc < 8; ++kc) {
      bf16x8 kf = *(const bf16x8*)&kl[((h * 8 + kc) * 64 + l) * 8];
      sacc = __builtin_amdgcn_mfma_f32_32x32x16_bf16(kf, qf[kc], sacc, 0, 0, 0);
    }
    // --- PV(i-1): pure register MFMA (8), interleaves with QK(i) ---
    #pragma unroll
    for (int u = 0; u < 2; ++u)
      #pragma unroll
      for (int ct = 0; ct < 4; ++ct)
        acco[ct] = __builtin_amdgcn_mfma_f32_32x32x16_bf16(vreg[ct * 2 + u], pf[u], acco[ct], 0, 0, 0);
    __builtin_amdgcn_s_setprio(0);
    __builtin_amdgcn_sched_barrier(0);   // pin vreg/pf refills below the PV reads

    // --- V(i) -> registers: this half's 8 frags (s = 2h+u) ---
    #pragma unroll
    for (int ct = 0; ct < 4; ++ct)
      #pragma unroll
      for (int u = 0; u < 2; ++u)
        vreg[ct * 2 + u] = *(const bf16x8*)&vl[((ct * 4 + 2 * h + u) * 64 + l) * 8];

    // --- softmax(i), no max: P = exp2(S); pairwise tree-sum ---
    #pragma unroll
    for (int r = 0; r < 16; ++r) sacc[r] = exp2f(sacc[r]);
    {
      float a0 = (sacc[0] + sacc[1]) + (sacc[2] + sacc[3]);
      float a1 = (sacc[4] + sacc[5]) + (sacc[6] + sacc[7]);
      float a2 = (sacc[8] + sacc[9]) + (sacc[10] + sacc[11]);
      float a3 = (sacc[12] + sacc[13]) + (sacc[14] + sacc[15]);
      lrun += (a0 + a1) + (a2 + a3);
    }
    // --- pack + permlane32_swap exchange -> PV B-fragments ---
    u32 gp[4][2];
    #pragma unroll
    for (int j = 0; j < 4; ++j) {
      gp[j][0] = cvtpk_bf16(sacc[j * 4 + 0], sacc[j * 4 + 1]);
      gp[j][1] = cvtpk_bf16(sacc[j * 4 + 2], sacc[j * 4 + 3]);
    }
    #pragma unroll
    for (int u = 0; u < 2; ++u) {
      u32 a0 = gp[2 * u][0], a1 = gp[2 * u][1];
      u32 b0 = gp[2 * u + 1][0], b1 = gp[2 * u + 1][1];
      // swap(a,b): a' = {a.lo, b.lo}, b' = {a.hi, b.hi}
      asm("v_permlane32_swap_b32 %0, %1" : "+v"(a0), "+v"(b0));
      asm("v_permlane32_swap_b32 %0, %1" : "+v"(a1), "+v"(b1));
      u32x4 fv; fv.x = a0; fv.y = a1; fv.z = b0; fv.w = b1;
      pf[u] = __builtin_bit_cast(bf16x8, fv);
    }
    __syncthreads();   // drains stage(i+1) + protects dbuf swap
  }

  // --- PV(31) (pure register) ---
  __builtin_amdgcn_s_setprio(1);
  #pragma unroll
  for (int u = 0; u < 2; ++u)
    #pragma unroll
    for (int ct = 0; ct < 4; ++ct)
      acco[ct] = __builtin_amdgcn_mfma_f32_32x32x16_bf16(vreg[ct * 2 + u], pf[u], acco[ct], 0, 0, 0);
  __builtin_amdgcn_s_setprio(0);

  float lt = lrun + __shfl_xor(lrun, 32, 64);

  // --- 2-way additive in-block merge (m-halves of same q-slot) ---
  if (w >= 2) {
    float* dst = lds.od[w - 2];
    #pragma unroll
    for (int ct = 0; ct < 4; ++ct)
      #pragma unroll
      for (int r = 0; r < 16; ++r) dst[(ct * 16 + r) * 64 + l] = acco[ct][r];
    lb[w - 2][l] = lt;
  }
  __syncthreads();
  if (w < 2) {
    const float* src = lds.od[w];
    #pragma unroll
    for (int ct = 0; ct < 4; ++ct)
      #pragma unroll
      for (int r = 0; r < 16; ++r) acco[ct][r] += src[(ct * 16 + r) * 64 + l];
    lt += lb[w][l];

    // --- normalize, then fuse skip = wskip @ up via MFMA into acco ---
    float inv = 1.0f / lt;
    #pragma unroll
    for (int ct = 0; ct < 4; ++ct)
      #pragma unroll
      for (int r = 0; r < 16; ++r) acco[ct][r] *= inv;

    const float* upb = up + (size_t)b * 128 * N_DIM;
    #pragma unroll
    for (int kc = 0; kc < 8; ++kc) {
      float uv[8];
      #pragma unroll
      for (int e = 0; e < 8; ++e)
        uv[e] = upb[(size_t)(kc * 16 + lh1 * 8 + e) * N_DIM + nq];
      u32x4 ufv;
      ufv.x = cvtpk_bf16(uv[0], uv[1]);
      ufv.y = cvtpk_bf16(uv[2], uv[3]);
      ufv.z = cvtpk_bf16(uv[4], uv[5]);
      ufv.w = cvtpk_bf16(uv[6], uv[7]);
      bf16x8 upf = __builtin_bit_cast(bf16x8, ufv);
      #pragma unroll
      for (int ct = 0; ct < 4; ++ct) {
        const float* wp = &wskip[(size_t)(ct * 32 + (l & 31)) * 128 + kc * 16 + lh1 * 8];
        float4 w0 = *(const float4*)wp;
        float4 w1 = *(const float4*)(wp + 4);
        u32x4 wfv;
        wfv.x = cvtpk_bf16(w0.x, w0.y);
        wfv.y = cvtpk_bf16(w0.z, w0.w);
        wfv.z = cvtpk_bf16(w1.x, w1.y);
        wfv.w = cvtpk_bf16(w1.z, w1.w);
        bf16x8 wsf = __builtin_bit_cast(bf16x8, wfv);
        acco[ct] = __builtin_amdgcn_mfma_f32_32x32x16_bf16(wsf, upf, acco[ct], 0, 0, 0);
      }
    }

    // --- store (single write; d_out never read) ---
    #pragma unroll
    for (int ct = 0; ct < 4; ++ct)
      #pragma unroll
      for (int r = 0; r < 16; ++r) {
        int c = ct * 32 + (r & 3) + 8 * (r >> 2) + 4 * lh1;
        out[((size_t)b * 128 + c) * N_DIM + nq] = acco[ct][r];
      }
  }
}

extern "C" void kernel_launch(void* const* d_in, const int* in_sizes, int n_in,
                              void* d_out, int out_size, void* d_ws, size_t ws_size,
                              hipStream_t stream) {
  const float* up    = (const float*)d_in[0];
  const float* down  = (const float*)d_in[1];
  const float* wq    = (const float*)d_in[2];
  const float* wk    = (const float*)d_in[3];
  const float* wv    = (const float*)d_in[4];
  const float* wskip = (const float*)d_in[5];
  float* out = (float*)d_out;

  u16* Qt  = (u16*)d_ws;                                   // 8 MB  [b][n][c]
  u16* Kt2 = Qt + (size_t)B_DIM * N_DIM * C_DIM;           // 2 MB  frag-major
  u16* Vp  = Kt2 + (size_t)B_DIM * M_DIM * C_DIM;          // 2 MB  frag-major

  const float qscale = (float)(1.4426950408889634 / sqrt(128.0));  // log2e/sqrt(C)

  hipLaunchKernelGGL((proj_kernel<0, -1>), dim3(N_DIM / 64, B_DIM), dim3(256), 0, stream,
                     up, wq, nullptr, Qt, nullptr, N_DIM, qscale);
  hipLaunchKernelGGL((proj_kernel<2, 3>), dim3(M_DIM / 64, B_DIM), dim3(256), 0, stream,
                     down, wk, wv, Kt2, Vp, M_DIM, 1.0f);
  hipLaunchKernelGGL((attn_kernel), dim3(512), dim3(256), 0, stream,
                     Qt, Kt2, Vp, up, wskip, out);
}

// Round 12
// 75.025 us; speedup vs baseline: 1.1875x; 1.0422x over previous
//
#include <hip/hip_runtime.h>
#include <hip/hip_bf16.h>
#include <math.h>

#define C_DIM 128
#define B_DIM 4
#define N_DIM 8192
#define M_DIM 2048
#define NT_KV 32   // M_DIM / 64 (64-m tiles)

typedef unsigned short u16;
typedef unsigned int u32;
typedef short bf16x8 __attribute__((ext_vector_type(8)));
typedef float f32x4 __attribute__((ext_vector_type(4)));
typedef float f32x16 __attribute__((ext_vector_type(16)));
typedef u32 u32x4 __attribute__((ext_vector_type(4)));

__device__ inline u16 f2bf(float f) {
  u32 u = __builtin_bit_cast(u32, f);
  u += 0x7fffu + ((u >> 16) & 1u);  // RNE, finite inputs
  return (u16)(u >> 16);
}
__device__ inline u32 cvtpk_bf16(float lo, float hi) {
  u32 r;
  asm("v_cvt_pk_bf16_f32 %0, %1, %2" : "=v"(r) : "v"(lo), "v"(hi));
  return r;
}

// ---------------- Projections: Y = W @ X_b, MFMA 16x16x32 ----------------
// MODE 0: Qt bf16 [b][x][o]; MODE 2: K frag-major; MODE 3: V frag-major.
template <int MODE>
__device__ inline void proj_pass(const float* __restrict__ W, float wscale,
                                 const u16* __restrict__ xt_s,
                                 u16* __restrict__ outh,
                                 int b, int X, int x0, int t) {
  const int l = t & 63, w = t >> 6, lr = l & 15, lh = (l >> 4) & 3;
  bf16x8 wf[2][4];
  #pragma unroll
  for (int ot = 0; ot < 2; ++ot)
    #pragma unroll
    for (int kc = 0; kc < 4; ++kc) {
      const float* wp = &W[(size_t)(w * 32 + ot * 16 + lr) * 128 + kc * 32 + lh * 8];
      float4 a0 = *(const float4*)wp;
      float4 a1 = *(const float4*)(wp + 4);
      bf16x8 f;
      f[0] = (short)f2bf(a0.x * wscale); f[1] = (short)f2bf(a0.y * wscale);
      f[2] = (short)f2bf(a0.z * wscale); f[3] = (short)f2bf(a0.w * wscale);
      f[4] = (short)f2bf(a1.x * wscale); f[5] = (short)f2bf(a1.y * wscale);
      f[6] = (short)f2bf(a1.z * wscale); f[7] = (short)f2bf(a1.w * wscale);
      wf[ot][kc] = f;
    }
  f32x4 acc[2][4];
  #pragma unroll
  for (int ot = 0; ot < 2; ++ot)
    #pragma unroll
    for (int xt = 0; xt < 4; ++xt) acc[ot][xt] = 0.f;

  #pragma unroll
  for (int xt = 0; xt < 4; ++xt) {
    int xx = xt * 16 + lr;
    #pragma unroll
    for (int kc = 0; kc < 4; ++kc) {
      bf16x8 bf = *(const bf16x8*)&xt_s[xx * 128 + ((kc * 32 + lh * 8) ^ ((xx & 15) << 3))];
      #pragma unroll
      for (int ot = 0; ot < 2; ++ot)
        acc[ot][xt] = __builtin_amdgcn_mfma_f32_16x16x32_bf16(wf[ot][kc], bf, acc[ot][xt], 0, 0, 0);
    }
  }
  #pragma unroll
  for (int ot = 0; ot < 2; ++ot) {
    int o0 = w * 32 + ot * 16 + lh * 4;
    #pragma unroll
    for (int xt = 0; xt < 4; ++xt) {
      int xg = x0 + xt * 16 + lr;
      if constexpr (MODE == 0) {
        u16 h[4];
        #pragma unroll
        for (int r = 0; r < 4; ++r) h[r] = f2bf(acc[ot][xt][r]);
        *(uint2*)&outh[((size_t)b * X + xg) * 128 + o0] = *(uint2*)h;
      } else if constexpr (MODE == 2) {
        int tt = xg >> 6, mt = (xg >> 5) & 1, ms = xg & 31;
        int kcK = o0 >> 4, lh1p = (o0 >> 3) & 1, e0 = o0 & 7;
        u16 h[4];
        #pragma unroll
        for (int r = 0; r < 4; ++r) h[r] = f2bf(acc[ot][xt][r]);
        size_t off = ((((size_t)(b * NT_KV + tt) * 2 + mt) * 8 + kcK) * 64 + (ms | (lh1p << 5))) * 8 + e0;
        *(uint2*)&outh[off] = *(uint2*)h;
      } else {
        int tt = xg >> 6, sv = (xg >> 4) & 3, lh1m = (xg >> 3) & 1, e = xg & 7;
        int ctv = o0 >> 5;
        #pragma unroll
        for (int r = 0; r < 4; ++r) {
          int cs = (o0 + r) & 31;
          size_t off = ((((size_t)(b * NT_KV + tt) * 4 + ctv) * 4 + sv) * 64 + (cs | (lh1m << 5))) * 8 + e;
          outh[off] = f2bf(acc[ot][xt][r]);
        }
      }
    }
  }
}

template <int MODE_A, int MODE_B>
__global__ __launch_bounds__(256, 2) void proj_kernel(
    const float* __restrict__ in, const float* __restrict__ WA, const float* __restrict__ WB,
    u16* __restrict__ hA, u16* __restrict__ hB, int X, float wscaleA) {
  __shared__ u16 xt_s[64 * 128];
  const int b = blockIdx.y, x0 = blockIdx.x * 64, t = threadIdx.x;
  #pragma unroll
  for (int pp = 0; pp < 8; ++pp) {
    int c = pp * 16 + (t >> 4);
    int x4 = (t & 15) * 4;
    float4 v = *(const float4*)&in[((size_t)b * 128 + c) * X + x0 + x4];
    xt_s[(x4 + 0) * 128 + (c ^ (((x4 + 0) & 15) << 3))] = f2bf(v.x);
    xt_s[(x4 + 1) * 128 + (c ^ (((x4 + 1) & 15) << 3))] = f2bf(v.y);
    xt_s[(x4 + 2) * 128 + (c ^ (((x4 + 2) & 15) << 3))] = f2bf(v.z);
    xt_s[(x4 + 3) * 128 + (c ^ (((x4 + 3) & 15) << 3))] = f2bf(v.w);
  }
  __syncthreads();
  proj_pass<MODE_A>(WA, wscaleA, xt_s, hA, b, X, x0, t);
  if constexpr (MODE_B >= 0)
    proj_pass<MODE_B>(WB, 1.0f, xt_s, hB, b, X, x0, t);
}

// ---------------- Flash attention, 32x32x16, swapped QK^T ----------------
// R9 config: 256 blocks x 512 thr (8 waves, 2/SIMD). Block = 128 q; wave w:
// q-slot w&3, m-half h=w>>2, ONE shared 64-m tile stream. NEW (T3/T4):
// 3-deep staging buffer + counted s_waitcnt vmcnt(4) + raw s_barrier —
// no vmcnt(0) drain in the main loop; prefetch spans 2 iterations.
// Deferred register-PV, no-max softmax, permlane32_swap exchange,
// 2-way additive LDS merge, fused skip epilogue.
__device__ inline void stage_kv(const u16* __restrict__ gK, const u16* __restrict__ gV,
                                u16* lK, u16* lV, int tile, int t) {
  const u16* ks = gK + (size_t)tile * 8192;
  const u16* vs = gV + (size_t)tile * 8192;
  #pragma unroll
  for (int i = 0; i < 2; ++i) {
    int ch = t + i * 512;
    __builtin_amdgcn_global_load_lds((const __attribute__((address_space(1))) void*)(ks + ch * 8),
                                     (__attribute__((address_space(3))) void*)(lK + ch * 8), 16, 0, 0);
    __builtin_amdgcn_global_load_lds((const __attribute__((address_space(1))) void*)(vs + ch * 8),
                                     (__attribute__((address_space(3))) void*)(lV + ch * 8), 16, 0, 0);
  }
}

__global__ __launch_bounds__(512, 2) void attn_kernel(
    const u16* __restrict__ Qt, const u16* __restrict__ Kt2,
    const u16* __restrict__ Vp, const float* __restrict__ up,
    const float* __restrict__ wskip, float* __restrict__ out) {
  __shared__ union {
    u16 kv[3][2][8192];   // [3-buf][K/V] = 96 KB
    float od[4][4096];    // merge: waves 4-7 dump unnormalized O (64 KB)
  } lds;
  __shared__ float lb[4][64];

  const int bid = blockIdx.x;
  const int xcd = bid & 7, b = xcd & 3, slot = bid >> 3;  // batch pinned per XCD pair
  const int n0 = ((xcd >> 2) * 32 + slot) * 128;
  const int t = threadIdx.x, w = t >> 6, l = t & 63, lh1 = l >> 5;
  const int h = w >> 2;          // m-half (mt)
  const int nq = n0 + (w & 3) * 32 + (l & 31);

  // Q fragments (B[k=c][j=q]): q = l&31, c = kc*16 + lh1*8 + e
  bf16x8 qf[8];
  #pragma unroll
  for (int kc = 0; kc < 8; ++kc)
    qf[kc] = *(const bf16x8*)&Qt[((size_t)b * N_DIM + nq) * 128 + kc * 16 + lh1 * 8];

  const u16* gK = Kt2 + (size_t)b * 262144;
  const u16* gV = Vp + (size_t)b * 262144;

  f32x16 acco[4];
  #pragma unroll
  for (int ct = 0; ct < 4; ++ct) acco[ct] = 0.f;
  float lrun = 0.f;

  // Deferred-PV state (zero-init so PV(-1) adds 0).
  bf16x8 pf[2];
  bf16x8 vreg[8];
  #pragma unroll
  for (int u = 0; u < 2; ++u) pf[u] = (bf16x8)0;
  #pragma unroll
  for (int x = 0; x < 8; ++x) vreg[x] = (bf16x8)0;

  stage_kv(gK, gV, lds.kv[0][0], lds.kv[0][1], 0, t);
  stage_kv(gK, gV, lds.kv[1][0], lds.kv[1][1], 1, t);

  int cur = 0;
  for (int i = 0; i < NT_KV; ++i) {
    // Counted wait: only the newest stage's 4 loads may remain in flight;
    // tile i's loads (issued 2 iters ago) are then guaranteed complete.
    asm volatile("s_waitcnt vmcnt(4)" ::: "memory");
    __builtin_amdgcn_sched_barrier(0);
    __builtin_amdgcn_s_barrier();     // raw barrier: NO vmcnt(0) drain
    __builtin_amdgcn_sched_barrier(0);
    if (i + 2 < NT_KV) {
      int nxt = cur + 2; if (nxt >= 3) nxt -= 3;
      stage_kv(gK, gV, lds.kv[nxt][0], lds.kv[nxt][1], i + 2, t);
    }
    const u16* kl = lds.kv[cur][0];
    const u16* vl = lds.kv[cur][1];

    // --- QK(i): this wave's m-half only (8 MFMAs, one sacc chain) ---
    f32x16 sacc = 0.f;
    __builtin_amdgcn_s_setprio(1);
    #pragma unroll
    for (int kc = 0; kc < 8; ++kc) {
      bf16x8 kf = *(const bf16x8*)&kl[((h * 8 + kc) * 64 + l) * 8];
      sacc = __builtin_amdgcn_mfma_f32_32x32x16_bf16(kf, qf[kc], sacc, 0, 0, 0);
    }
    // --- PV(i-1): pure register MFMA (8), interleaves with QK(i) ---
    #pragma unroll
    for (int u = 0; u < 2; ++u)
      #pragma unroll
      for (int ct = 0; ct < 4; ++ct)
        acco[ct] = __builtin_amdgcn_mfma_f32_32x32x16_bf16(vreg[ct * 2 + u], pf[u], acco[ct], 0, 0, 0);
    __builtin_amdgcn_s_setprio(0);
    __builtin_amdgcn_sched_barrier(0);   // pin vreg/pf refills below the PV reads

    // --- V(i) -> registers: this half's 8 frags (s = 2h+u) ---
    #pragma unroll
    for (int ct = 0; ct < 4; ++ct)
      #pragma unroll
      for (int u = 0; u < 2; ++u)
        vreg[ct * 2 + u] = *(const bf16x8*)&vl[((ct * 4 + 2 * h + u) * 64 + l) * 8];

    // --- softmax(i), no max: P = exp2(S); pairwise tree-sum ---
    #pragma unroll
    for (int r = 0; r < 16; ++r) sacc[r] = exp2f(sacc[r]);
    {
      float a0 = (sacc[0] + sacc[1]) + (sacc[2] + sacc[3]);
      float a1 = (sacc[4] + sacc[5]) + (sacc[6] + sacc[7]);
      float a2 = (sacc[8] + sacc[9]) + (sacc[10] + sacc[11]);
      float a3 = (sacc[12] + sacc[13]) + (sacc[14] + sacc[15]);
      lrun += (a0 + a1) + (a2 + a3);
    }
    // --- pack + permlane32_swap exchange -> PV B-fragments ---
    u32 gp[4][2];
    #pragma unroll
    for (int j = 0; j < 4; ++j) {
      gp[j][0] = cvtpk_bf16(sacc[j * 4 + 0], sacc[j * 4 + 1]);
      gp[j][1] = cvtpk_bf16(sacc[j * 4 + 2], sacc[j * 4 + 3]);
    }
    #pragma unroll
    for (int u = 0; u < 2; ++u) {
      u32 a0 = gp[2 * u][0], a1 = gp[2 * u][1];
      u32 b0 = gp[2 * u + 1][0], b1 = gp[2 * u + 1][1];
      // swap(a,b): a' = {a.lo, b.lo}, b' = {a.hi, b.hi}
      asm("v_permlane32_swap_b32 %0, %1" : "+v"(a0), "+v"(b0));
      asm("v_permlane32_swap_b32 %0, %1" : "+v"(a1), "+v"(b1));
      u32x4 fv; fv.x = a0; fv.y = a1; fv.z = b0; fv.w = b1;
      pf[u] = __builtin_bit_cast(bf16x8, fv);
    }
    cur += 1; if (cur >= 3) cur = 0;
  }

  // --- PV(31) (pure register) ---
  __builtin_amdgcn_s_setprio(1);
  #pragma unroll
  for (int u = 0; u < 2; ++u)
    #pragma unroll
    for (int ct = 0; ct < 4; ++ct)
      acco[ct] = __builtin_amdgcn_mfma_f32_32x32x16_bf16(vreg[ct * 2 + u], pf[u], acco[ct], 0, 0, 0);
  __builtin_amdgcn_s_setprio(0);

  float lt = lrun + __shfl_xor(lrun, 32, 64);

  __syncthreads();   // full drain once: protect od-aliasing of kv buffers

  // --- 2-way additive in-block merge (m-halves of same q-slot) ---
  if (w >= 4) {
    float* dst = lds.od[w - 4];
    #pragma unroll
    for (int ct = 0; ct < 4; ++ct)
      #pragma unroll
      for (int r = 0; r < 16; ++r) dst[(ct * 16 + r) * 64 + l] = acco[ct][r];
    lb[w - 4][l] = lt;
  }
  __syncthreads();
  if (w < 4) {
    const float* src = lds.od[w];
    #pragma unroll
    for (int ct = 0; ct < 4; ++ct)
      #pragma unroll
      for (int r = 0; r < 16; ++r) acco[ct][r] += src[(ct * 16 + r) * 64 + l];
    lt += lb[w][l];

    // --- normalize, then fuse skip = wskip @ up via MFMA into acco ---
    float inv = 1.0f / lt;
    #pragma unroll
    for (int ct = 0; ct < 4; ++ct)
      #pragma unroll
      for (int r = 0; r < 16; ++r) acco[ct][r] *= inv;

    const float* upb = up + (size_t)b * 128 * N_DIM;
    #pragma unroll
    for (int kc = 0; kc < 8; ++kc) {
      float uv[8];
      #pragma unroll
      for (int e = 0; e < 8; ++e)
        uv[e] = upb[(size_t)(kc * 16 + lh1 * 8 + e) * N_DIM + nq];
      u32x4 ufv;
      ufv.x = cvtpk_bf16(uv[0], uv[1]);
      ufv.y = cvtpk_bf16(uv[2], uv[3]);
      ufv.z = cvtpk_bf16(uv[4], uv[5]);
      ufv.w = cvtpk_bf16(uv[6], uv[7]);
      bf16x8 upf = __builtin_bit_cast(bf16x8, ufv);
      #pragma unroll
      for (int ct = 0; ct < 4; ++ct) {
        const float* wp = &wskip[(size_t)(ct * 32 + (l & 31)) * 128 + kc * 16 + lh1 * 8];
        float4 w0 = *(const float4*)wp;
        float4 w1 = *(const float4*)(wp + 4);
        u32x4 wfv;
        wfv.x = cvtpk_bf16(w0.x, w0.y);
        wfv.y = cvtpk_bf16(w0.z, w0.w);
        wfv.z = cvtpk_bf16(w1.x, w1.y);
        wfv.w = cvtpk_bf16(w1.z, w1.w);
        bf16x8 wsf = __builtin_bit_cast(bf16x8, wfv);
        acco[ct] = __builtin_amdgcn_mfma_f32_32x32x16_bf16(wsf, upf, acco[ct], 0, 0, 0);
      }
    }

    // --- store (single write; d_out never read) ---
    #pragma unroll
    for (int ct = 0; ct < 4; ++ct)
      #pragma unroll
      for (int r = 0; r < 16; ++r) {
        int c = ct * 32 + (r & 3) + 8 * (r >> 2) + 4 * lh1;
        out[((size_t)b * 128 + c) * N_DIM + nq] = acco[ct][r];
      }
  }
}

extern "C" void kernel_launch(void* const* d_in, const int* in_sizes, int n_in,
                              void* d_out, int out_size, void* d_ws, size_t ws_size,
                              hipStream_t stream) {
  const float* up    = (const float*)d_in[0];
  const float* down  = (const float*)d_in[1];
  const float* wq    = (const float*)d_in[2];
  const float* wk    = (const float*)d_in[3];
  const float* wv    = (const float*)d_in[4];
  const float* wskip = (const float*)d_in[5];
  float* out = (float*)d_out;

  u16* Qt  = (u16*)d_ws;                                   // 8 MB  [b][n][c]
  u16* Kt2 = Qt + (size_t)B_DIM * N_DIM * C_DIM;           // 2 MB  frag-major
  u16* Vp  = Kt2 + (size_t)B_DIM * M_DIM * C_DIM;          // 2 MB  frag-major

  const float qscale = (float)(1.4426950408889634 / sqrt(128.0));  // log2e/sqrt(C)

  hipLaunchKernelGGL((proj_kernel<0, -1>), dim3(N_DIM / 64, B_DIM), dim3(256), 0, stream,
                     up, wq, nullptr, Qt, nullptr, N_DIM, qscale);
  hipLaunchKernelGGL((proj_kernel<2, 3>), dim3(M_DIM / 64, B_DIM), dim3(256), 0, stream,
                     down, wk, wv, Kt2, Vp, M_DIM, 1.0f);
  hipLaunchKernelGGL((attn_kernel), dim3(256), dim3(512), 0, stream,
                     Qt, Kt2, Vp, up, wskip, out);
}

// Round 14
// 70.320 us; speedup vs baseline: 1.2669x; 1.0669x over previous
//
#include <hip/hip_runtime.h>
#include <hip/hip_bf16.h>
#include <math.h>

#define C_DIM 128
#define B_DIM 4
#define N_DIM 8192
#define M_DIM 2048
#define NT_KV 32   // M_DIM / 64 (64-m tiles)

typedef unsigned short u16;
typedef unsigned int u32;
typedef short bf16x8 __attribute__((ext_vector_type(8)));
typedef float f32x4 __attribute__((ext_vector_type(4)));
typedef float f32x16 __attribute__((ext_vector_type(16)));
typedef u32 u32x4 __attribute__((ext_vector_type(4)));

__device__ inline u16 f2bf(float f) {
  u32 u = __builtin_bit_cast(u32, f);
  u += 0x7fffu + ((u >> 16) & 1u);  // RNE, finite inputs
  return (u16)(u >> 16);
}
__device__ inline u32 cvtpk_bf16(float lo, float hi) {
  u32 r;
  asm("v_cvt_pk_bf16_f32 %0, %1, %2" : "=v"(r) : "v"(lo), "v"(hi));
  return r;
}

// ---------------- Projections: Y = W @ X_b, MFMA 16x16x32 ----------------
// MODE 0: Qt bf16 [b][x][o]; MODE 2: K frag-major; MODE 3: V frag-major.
template <int MODE>
__device__ inline void proj_pass(const float* __restrict__ W, float wscale,
                                 const u16* __restrict__ xt_s,
                                 u16* __restrict__ outh,
                                 int b, int X, int x0, int t) {
  const int l = t & 63, w = t >> 6, lr = l & 15, lh = (l >> 4) & 3;
  bf16x8 wf[2][4];
  #pragma unroll
  for (int ot = 0; ot < 2; ++ot)
    #pragma unroll
    for (int kc = 0; kc < 4; ++kc) {
      const float* wp = &W[(size_t)(w * 32 + ot * 16 + lr) * 128 + kc * 32 + lh * 8];
      float4 a0 = *(const float4*)wp;
      float4 a1 = *(const float4*)(wp + 4);
      bf16x8 f;
      f[0] = (short)f2bf(a0.x * wscale); f[1] = (short)f2bf(a0.y * wscale);
      f[2] = (short)f2bf(a0.z * wscale); f[3] = (short)f2bf(a0.w * wscale);
      f[4] = (short)f2bf(a1.x * wscale); f[5] = (short)f2bf(a1.y * wscale);
      f[6] = (short)f2bf(a1.z * wscale); f[7] = (short)f2bf(a1.w * wscale);
      wf[ot][kc] = f;
    }
  f32x4 acc[2][4];
  #pragma unroll
  for (int ot = 0; ot < 2; ++ot)
    #pragma unroll
    for (int xt = 0; xt < 4; ++xt) acc[ot][xt] = 0.f;

  #pragma unroll
  for (int xt = 0; xt < 4; ++xt) {
    int xx = xt * 16 + lr;
    #pragma unroll
    for (int kc = 0; kc < 4; ++kc) {
      bf16x8 bf = *(const bf16x8*)&xt_s[xx * 128 + ((kc * 32 + lh * 8) ^ ((xx & 15) << 3))];
      #pragma unroll
      for (int ot = 0; ot < 2; ++ot)
        acc[ot][xt] = __builtin_amdgcn_mfma_f32_16x16x32_bf16(wf[ot][kc], bf, acc[ot][xt], 0, 0, 0);
    }
  }
  #pragma unroll
  for (int ot = 0; ot < 2; ++ot) {
    int o0 = w * 32 + ot * 16 + lh * 4;
    #pragma unroll
    for (int xt = 0; xt < 4; ++xt) {
      int xg = x0 + xt * 16 + lr;
      if constexpr (MODE == 0) {
        u16 h[4];
        #pragma unroll
        for (int r = 0; r < 4; ++r) h[r] = f2bf(acc[ot][xt][r]);
        *(uint2*)&outh[((size_t)b * X + xg) * 128 + o0] = *(uint2*)h;
      } else if constexpr (MODE == 2) {
        int tt = xg >> 6, mt = (xg >> 5) & 1, ms = xg & 31;
        int kcK = o0 >> 4, lh1p = (o0 >> 3) & 1, e0 = o0 & 7;
        u16 h[4];
        #pragma unroll
        for (int r = 0; r < 4; ++r) h[r] = f2bf(acc[ot][xt][r]);
        size_t off = ((((size_t)(b * NT_KV + tt) * 2 + mt) * 8 + kcK) * 64 + (ms | (lh1p << 5))) * 8 + e0;
        *(uint2*)&outh[off] = *(uint2*)h;
      } else {
        int tt = xg >> 6, sv = (xg >> 4) & 3, lh1m = (xg >> 3) & 1, e = xg & 7;
        int ctv = o0 >> 5;
        #pragma unroll
        for (int r = 0; r < 4; ++r) {
          int cs = (o0 + r) & 31;
          size_t off = ((((size_t)(b * NT_KV + tt) * 4 + ctv) * 4 + sv) * 64 + (cs | (lh1m << 5))) * 8 + e;
          outh[off] = f2bf(acc[ot][xt][r]);
        }
      }
    }
  }
}

// One fused dispatch: blocks [0,512) do the Q projection on `up`;
// blocks [512,640) do K+V projections on `down`. Wave-uniform branch,
// identical proj_pass bodies (verified rounds 2-12).
__global__ __launch_bounds__(256, 2) void proj_all(
    const float* __restrict__ up, const float* __restrict__ down,
    const float* __restrict__ wq, const float* __restrict__ wk,
    const float* __restrict__ wv, u16* __restrict__ Qt,
    u16* __restrict__ Kt2, u16* __restrict__ Vp, float qscale) {
  __shared__ u16 xt_s[64 * 128];
  const int bid = blockIdx.x, t = threadIdx.x;
  const bool isQ = bid < 512;
  const int sub = isQ ? bid : bid - 512;
  const int b = sub & 3;
  const int x0 = (sub >> 2) * 64;
  const int X = isQ ? N_DIM : M_DIM;
  const float* in = isQ ? up : down;

  #pragma unroll
  for (int pp = 0; pp < 8; ++pp) {
    int c = pp * 16 + (t >> 4);
    int x4 = (t & 15) * 4;
    float4 v = *(const float4*)&in[((size_t)b * 128 + c) * X + x0 + x4];
    xt_s[(x4 + 0) * 128 + (c ^ (((x4 + 0) & 15) << 3))] = f2bf(v.x);
    xt_s[(x4 + 1) * 128 + (c ^ (((x4 + 1) & 15) << 3))] = f2bf(v.y);
    xt_s[(x4 + 2) * 128 + (c ^ (((x4 + 2) & 15) << 3))] = f2bf(v.z);
    xt_s[(x4 + 3) * 128 + (c ^ (((x4 + 3) & 15) << 3))] = f2bf(v.w);
  }
  __syncthreads();
  if (isQ) {
    proj_pass<0>(wq, qscale, xt_s, Qt, b, X, x0, t);
  } else {
    proj_pass<2>(wk, 1.0f, xt_s, Kt2, b, X, x0, t);
    proj_pass<3>(wv, 1.0f, xt_s, Vp, b, X, x0, t);
  }
}

// ---------------- Flash attention, 32x32x16, swapped QK^T ----------------
// R9 (best measured): 256 blocks x 512 thr (8 waves, 2/SIMD). Block = 128 q;
// wave w: q-slot w&3, m-half h=w>>2, ONE shared 64-m tile stream, 64 KB dbuf.
// Deferred register-PV overlapping QK, no-max softmax, permlane32_swap
// P-exchange, 2-way additive LDS merge, fused skip epilogue.
__device__ inline void stage_kv(const u16* __restrict__ gK, const u16* __restrict__ gV,
                                u16* lK, u16* lV, int tile, int t) {
  const u16* ks = gK + (size_t)tile * 8192;
  const u16* vs = gV + (size_t)tile * 8192;
  #pragma unroll
  for (int i = 0; i < 2; ++i) {
    int ch = t + i * 512;
    __builtin_amdgcn_global_load_lds((const __attribute__((address_space(1))) void*)(ks + ch * 8),
                                     (__attribute__((address_space(3))) void*)(lK + ch * 8), 16, 0, 0);
    __builtin_amdgcn_global_load_lds((const __attribute__((address_space(1))) void*)(vs + ch * 8),
                                     (__attribute__((address_space(3))) void*)(lV + ch * 8), 16, 0, 0);
  }
}

__global__ __launch_bounds__(512, 2) void attn_kernel(
    const u16* __restrict__ Qt, const u16* __restrict__ Kt2,
    const u16* __restrict__ Vp, const float* __restrict__ up,
    const float* __restrict__ wskip, float* __restrict__ out) {
  __shared__ union {
    u16 kv[2][2][8192];   // [dbuf][K/V] = 64 KB
    float od[4][4096];    // merge: waves 4-7 dump unnormalized O (64 KB)
  } lds;
  __shared__ float lb[4][64];

  const int bid = blockIdx.x;
  const int xcd = bid & 7, b = xcd & 3, slot = bid >> 3;  // batch pinned per XCD pair
  const int n0 = ((xcd >> 2) * 32 + slot) * 128;
  const int t = threadIdx.x, w = t >> 6, l = t & 63, lh1 = l >> 5;
  const int h = w >> 2;          // m-half (mt)
  const int nq = n0 + (w & 3) * 32 + (l & 31);

  // Q fragments (B[k=c][j=q]): q = l&31, c = kc*16 + lh1*8 + e
  bf16x8 qf[8];
  #pragma unroll
  for (int kc = 0; kc < 8; ++kc)
    qf[kc] = *(const bf16x8*)&Qt[((size_t)b * N_DIM + nq) * 128 + kc * 16 + lh1 * 8];

  const u16* gK = Kt2 + (size_t)b * 262144;
  const u16* gV = Vp + (size_t)b * 262144;

  f32x16 acco[4];
  #pragma unroll
  for (int ct = 0; ct < 4; ++ct) acco[ct] = 0.f;
  float lrun = 0.f;

  // Deferred-PV state (zero-init so PV(-1) adds 0).
  bf16x8 pf[2];
  bf16x8 vreg[8];
  #pragma unroll
  for (int u = 0; u < 2; ++u) pf[u] = (bf16x8)0;
  #pragma unroll
  for (int x = 0; x < 8; ++x) vreg[x] = (bf16x8)0;

  stage_kv(gK, gV, lds.kv[0][0], lds.kv[0][1], 0, t);
  __syncthreads();

  #pragma unroll 2
  for (int i = 0; i < NT_KV; ++i) {
    const int cur = i & 1;
    if (i + 1 < NT_KV)
      stage_kv(gK, gV, lds.kv[cur ^ 1][0], lds.kv[cur ^ 1][1], i + 1, t);
    const u16* kl = lds.kv[cur][0];
    const u16* vl = lds.kv[cur][1];

    // --- QK(i): this wave's m-half only (8 MFMAs, one sacc chain) ---
    f32x16 sacc = 0.f;
    __builtin_amdgcn_s_setprio(1);
    #pragma unroll
    for (int kc = 0; kc < 8; ++kc) {
      bf16x8 kf = *(const bf16x8*)&kl[((h * 8 + kc) * 64 + l) * 8];
      sacc = __builtin_amdgcn_mfma_f32_32x32x16_bf16(kf, qf[kc], sacc, 0, 0, 0);
    }
    // --- PV(i-1): pure register MFMA (8), interleaves with QK(i) ---
    #pragma unroll
    for (int u = 0; u < 2; ++u)
      #pragma unroll
      for (int ct = 0; ct < 4; ++ct)
        acco[ct] = __builtin_amdgcn_mfma_f32_32x32x16_bf16(vreg[ct * 2 + u], pf[u], acco[ct], 0, 0, 0);
    __builtin_amdgcn_s_setprio(0);
    __builtin_amdgcn_sched_barrier(0);   // pin vreg/pf refills below the PV reads

    // --- V(i) -> registers: this half's 8 frags (s = 2h+u) ---
    #pragma unroll
    for (int ct = 0; ct < 4; ++ct)
      #pragma unroll
      for (int u = 0; u < 2; ++u)
        vreg[ct * 2 + u] = *(const bf16x8*)&vl[((ct * 4 + 2 * h + u) * 64 + l) * 8];

    // --- softmax(i), no max: P = exp2(S); pairwise tree-sum ---
    #pragma unroll
    for (int r = 0; r < 16; ++r) sacc[r] = exp2f(sacc[r]);
    {
      float a0 = (sacc[0] + sacc[1]) + (sacc[2] + sacc[3]);
      float a1 = (sacc[4] + sacc[5]) + (sacc[6] + sacc[7]);
      float a2 = (sacc[8] + sacc[9]) + (sacc[10] + sacc[11]);
      float a3 = (sacc[12] + sacc[13]) + (sacc[14] + sacc[15]);
      lrun += (a0 + a1) + (a2 + a3);
    }
    // --- pack + permlane32_swap exchange -> PV B-fragments ---
    u32 gp[4][2];
    #pragma unroll
    for (int j = 0; j < 4; ++j) {
      gp[j][0] = cvtpk_bf16(sacc[j * 4 + 0], sacc[j * 4 + 1]);
      gp[j][1] = cvtpk_bf16(sacc[j * 4 + 2], sacc[j * 4 + 3]);
    }
    #pragma unroll
    for (int u = 0; u < 2; ++u) {
      u32 a0 = gp[2 * u][0], a1 = gp[2 * u][1];
      u32 b0 = gp[2 * u + 1][0], b1 = gp[2 * u + 1][1];
      // swap(a,b): a' = {a.lo, b.lo}, b' = {a.hi, b.hi}
      asm("v_permlane32_swap_b32 %0, %1" : "+v"(a0), "+v"(b0));
      asm("v_permlane32_swap_b32 %0, %1" : "+v"(a1), "+v"(b1));
      u32x4 fv; fv.x = a0; fv.y = a1; fv.z = b0; fv.w = b1;
      pf[u] = __builtin_bit_cast(bf16x8, fv);
    }
    __syncthreads();   // drains stage(i+1) + protects dbuf swap
  }

  // --- PV(31) (pure register) ---
  __builtin_amdgcn_s_setprio(1);
  #pragma unroll
  for (int u = 0; u < 2; ++u)
    #pragma unroll
    for (int ct = 0; ct < 4; ++ct)
      acco[ct] = __builtin_amdgcn_mfma_f32_32x32x16_bf16(vreg[ct * 2 + u], pf[u], acco[ct], 0, 0, 0);
  __builtin_amdgcn_s_setprio(0);

  float lt = lrun + __shfl_xor(lrun, 32, 64);

  // --- 2-way additive in-block merge (m-halves of same q-slot) ---
  if (w >= 4) {
    float* dst = lds.od[w - 4];
    #pragma unroll
    for (int ct = 0; ct < 4; ++ct)
      #pragma unroll
      for (int r = 0; r < 16; ++r) dst[(ct * 16 + r) * 64 + l] = acco[ct][r];
    lb[w - 4][l] = lt;
  }
  __syncthreads();
  if (w < 4) {
    const float* src = lds.od[w];
    #pragma unroll
    for (int ct = 0; ct < 4; ++ct)
      #pragma unroll
      for (int r = 0; r < 16; ++r) acco[ct][r] += src[(ct * 16 + r) * 64 + l];
    lt += lb[w][l];

    // --- normalize, then fuse skip = wskip @ up via MFMA into acco ---
    float inv = 1.0f / lt;
    #pragma unroll
    for (int ct = 0; ct < 4; ++ct)
      #pragma unroll
      for (int r = 0; r < 16; ++r) acco[ct][r] *= inv;

    const float* upb = up + (size_t)b * 128 * N_DIM;
    #pragma unroll
    for (int kc = 0; kc < 8; ++kc) {
      float uv[8];
      #pragma unroll
      for (int e = 0; e < 8; ++e)
        uv[e] = upb[(size_t)(kc * 16 + lh1 * 8 + e) * N_DIM + nq];
      u32x4 ufv;
      ufv.x = cvtpk_bf16(uv[0], uv[1]);
      ufv.y = cvtpk_bf16(uv[2], uv[3]);
      ufv.z = cvtpk_bf16(uv[4], uv[5]);
      ufv.w = cvtpk_bf16(uv[6], uv[7]);
      bf16x8 upf = __builtin_bit_cast(bf16x8, ufv);
      #pragma unroll
      for (int ct = 0; ct < 4; ++ct) {
        const float* wp = &wskip[(size_t)(ct * 32 + (l & 31)) * 128 + kc * 16 + lh1 * 8];
        float4 w0 = *(const float4*)wp;
        float4 w1 = *(const float4*)(wp + 4);
        u32x4 wfv;
        wfv.x = cvtpk_bf16(w0.x, w0.y);
        wfv.y = cvtpk_bf16(w0.z, w0.w);
        wfv.z = cvtpk_bf16(w1.x, w1.y);
        wfv.w = cvtpk_bf16(w1.z, w1.w);
        bf16x8 wsf = __builtin_bit_cast(bf16x8, wfv);
        acco[ct] = __builtin_amdgcn_mfma_f32_32x32x16_bf16(wsf, upf, acco[ct], 0, 0, 0);
      }
    }

    // --- store (single write; d_out never read) ---
    #pragma unroll
    for (int ct = 0; ct < 4; ++ct)
      #pragma unroll
      for (int r = 0; r < 16; ++r) {
        int c = ct * 32 + (r & 3) + 8 * (r >> 2) + 4 * lh1;
        out[((size_t)b * 128 + c) * N_DIM + nq] = acco[ct][r];
      }
  }
}

extern "C" void kernel_launch(void* const* d_in, const int* in_sizes, int n_in,
                              void* d_out, int out_size, void* d_ws, size_t ws_size,
                              hipStream_t stream) {
  const float* up    = (const float*)d_in[0];
  const float* down  = (const float*)d_in[1];
  const float* wq    = (const float*)d_in[2];
  const float* wk    = (const float*)d_in[3];
  const float* wv    = (const float*)d_in[4];
  const float* wskip = (const float*)d_in[5];
  float* out = (float*)d_out;

  u16* Qt  = (u16*)d_ws;                                   // 8 MB  [b][n][c]
  u16* Kt2 = Qt + (size_t)B_DIM * N_DIM * C_DIM;           // 2 MB  frag-major
  u16* Vp  = Kt2 + (size_t)B_DIM * M_DIM * C_DIM;          // 2 MB  frag-major

  const float qscale = (float)(1.4426950408889634 / sqrt(128.0));  // log2e/sqrt(C)

  hipLaunchKernelGGL((proj_all), dim3(640), dim3(256), 0, stream,
                     up, down, wq, wk, wv, Qt, Kt2, Vp, qscale);
  hipLaunchKernelGGL((attn_kernel), dim3(256), dim3(512), 0, stream,
                     Qt, Kt2, Vp, up, wskip, out);
}